// Round 3
// baseline (257.757 us; speedup 1.0000x reference)
//
#include <hip/hip_runtime.h>
#include <hip/hip_bf16.h>

typedef __attribute__((ext_vector_type(8))) __bf16 bf16x8;
typedef __attribute__((ext_vector_type(4))) __bf16 bf16x4;
typedef __attribute__((ext_vector_type(4))) float  f32x4;
typedef __attribute__((ext_vector_type(4))) int    i32x4;

namespace {
constexpr int kB   = 16;
constexpr int kSQ  = 2048;
constexpr int kSK  = 2048;
constexpr int kD   = 64;
constexpr int kQB  = 16;                 // q-rows per block
constexpr int kNBLK = 8;                 // blocks per wg (128 rows)
constexpr float kScaleLog2e = 0.18033688011112042f; // (1/8)*log2(e)

constexpr int kPBytes   = kQB * kSK * 2;             // 65536 per P buffer
constexpr int kCStride  = 68;                        // cpart row stride (f32)
constexpr int kCpartOff = 2 * kPBytes;               // 131072
constexpr int kCpartBytes = 2 * 2 * kQB * kCStride * 4; // 17408
constexpr int kSumsOff  = kCpartOff + kCpartBytes;   // 148480
constexpr int kLdsTot   = kSumsOff + 4 * 8 * kQB * 4; // 150528
}

// Software-pipelined, wave-specialized fused attention.
// Waves 0-3 (compute): pass1(QK^T swapped, mask, exp -> P in LDS) of block j+1,
//   then PV(block j). Waves 4-7 (store): attn stores(block j), ctx fin(j-1).
// Reads (mask/K/V) and writes (attn/ctx) overlap on every CU continuously.
__global__ __launch_bounds__(512, 2)
void sdpa_pipe(const float* __restrict__ Qg, const float* __restrict__ Kg,
               const float* __restrict__ Vg, const int* __restrict__ Mg,
               float* __restrict__ ctxOut, float* __restrict__ attnOut)
{
  __shared__ __align__(16) char lds[kLdsTot];
  float* cpart  = reinterpret_cast<float*>(lds + kCpartOff); // [2buf][2kh][16][68]
  float* sums_p = reinterpret_cast<float*>(lds + kSumsOff);  // [4blk][8w][16row]

  const int tid  = threadIdx.x;
  const int wid  = tid >> 6;
  const int lane = tid & 63;
  const int l15  = lane & 15;
  const int kg   = lane >> 4;            // 0..3

  // XCD-bijective swizzle: 256 wgs, 32 contiguous per XCD (2 batches).
  const int wg = (blockIdx.x & 7) * 32 + (blockIdx.x >> 3);
  const int b  = wg >> 4;                // 16 wgs per batch
  const int q_base = (wg & 15) * (kQB * kNBLK);

  const float* Qb = Qg + (size_t)b * kSQ * kD;
  const float* Kb = Kg + (size_t)b * kSK * kD;
  const float* Vb = Vg + (size_t)b * kSK * kD;
  const int*   Mb = Mg + (size_t)b * kSQ * kSK;

  // ---------- pass 1: swapped QK^T for one 16-row block ----------
  auto pass1 = [&](int blk, int keyBase, int nTiles) {
    char* Pb = lds + (blk & 1) * kPBytes;
    const int qrow = q_base + blk * kQB + l15;     // this lane's q (C col)
    const float* qp = Qb + (size_t)qrow * kD + kg * 8;
    bf16x8 qf0, qf1;
#pragma unroll
    for (int e = 0; e < 8; ++e) { qf0[e] = (__bf16)qp[e]; qf1[e] = (__bf16)qp[32 + e]; }
    const int* mrow = Mb + (size_t)qrow * kSK;
    float lsum = 0.f;
    for (int t = 0; t < nTiles; ++t) {
      const int k0 = keyBase + t * 16;
      const float* kp = Kb + (size_t)(k0 + l15) * kD + kg * 8;
      bf16x8 kf0, kf1;
#pragma unroll
      for (int e = 0; e < 8; ++e) { kf0[e] = (__bf16)kp[e]; kf1[e] = (__bf16)kp[32 + e]; }
      const i32x4 mv = *reinterpret_cast<const i32x4*>(mrow + k0 + kg * 4);
      f32x4 acc = {0.f, 0.f, 0.f, 0.f};
      acc = __builtin_amdgcn_mfma_f32_16x16x32_bf16(kf0, qf0, acc, 0, 0, 0);
      acc = __builtin_amdgcn_mfma_f32_16x16x32_bf16(kf1, qf1, acc, 0, 0, 0);
      // lane holds S[key = k0+kg*4+r][q = qrow], r=0..3 (4 consecutive keys)
      bf16x4 p4;
#pragma unroll
      for (int r = 0; r < 4; ++r) {
        const float pv = mv[r] ? 0.f
                               : __builtin_amdgcn_exp2f(acc[r] * kScaleLog2e);
        lsum += pv;
        p4[r] = (__bf16)pv;
      }
      const int byte = ((l15 << 12) + ((k0 + kg * 4) << 1)) ^ (l15 << 4);
      *reinterpret_cast<bf16x4*>(Pb + byte) = p4;   // 8B swizzled write
    }
    lsum += __shfl_xor(lsum, 16, 64);
    lsum += __shfl_xor(lsum, 32, 64);
    if (lane < 16) {
      float* sp = sums_p + (blk & 3) * (8 * kQB);
      sp[wid * kQB + l15] = lsum;
      if (nTiles == 32) sp[(wid + 4) * kQB + l15] = 0.f; // main: only 4 waves
    }
  };

  // ---------- PV for one block (compute waves, wid 0..3) ----------
  auto pv_phase = [&](int blk) {
    const char* Pb = lds + (blk & 1) * kPBytes;
    const int kh = wid & 1, dh = wid >> 1;
    const int dcol0 = dh * 32 + l15, dcol1 = dcol0 + 16;
    f32x4 acc0 = {0.f, 0.f, 0.f, 0.f}, acc1 = {0.f, 0.f, 0.f, 0.f};
    for (int ks = 0; ks < 32; ++ks) {
      const int kk = kh * 1024 + ks * 32;
      const int byte = ((l15 << 12) + ((kk + kg * 8) << 1)) ^ (l15 << 4);
      const bf16x8 af = *reinterpret_cast<const bf16x8*>(Pb + byte);
      const float* vp = Vb + (size_t)(kk + kg * 8) * kD;
      bf16x8 v0, v1;
#pragma unroll
      for (int e = 0; e < 8; ++e) {
        v0[e] = (__bf16)vp[e * kD + dcol0];
        v1[e] = (__bf16)vp[e * kD + dcol1];
      }
      acc0 = __builtin_amdgcn_mfma_f32_16x16x32_bf16(af, v0, acc0, 0, 0, 0);
      acc1 = __builtin_amdgcn_mfma_f32_16x16x32_bf16(af, v1, acc1, 0, 0, 0);
    }
    float* cp = cpart + ((blk & 1) * 2 + kh) * (kQB * kCStride);
#pragma unroll
    for (int r = 0; r < 4; ++r) {
      cp[(kg * 4 + r) * kCStride + dcol0] = acc0[r];
      cp[(kg * 4 + r) * kCStride + dcol1] = acc1[r];
    }
  };

  // ---------- attn stores for one block (store waves, wid 4..7) ----------
  auto attn_store = [&](int blk) {
    const char* Pb = lds + (blk & 1) * kPBytes;
    const float* sp = sums_p + (blk & 3) * (8 * kQB);
    const int sw = wid - 4;
#pragma unroll
    for (int rr = 0; rr < 4; ++rr) {
      const int row = sw * 4 + rr;
      float l = 0.f;
#pragma unroll
      for (int w = 0; w < 8; ++w) l += sp[w * kQB + row];
      const float inv = 1.0f / l;
      float* arow = attnOut + ((size_t)(b * kSQ) + q_base + blk * kQB + row) * kSK;
      const int xr = row << 4;
#pragma unroll
      for (int ch = 0; ch < 8; ++ch) {
        const int col = ch * 256 + lane * 4;
        const bf16x4 p4 = *reinterpret_cast<const bf16x4*>(
            Pb + (((row << 12) + (col << 1)) ^ xr));
        float4 o;
        o.x = (float)p4[0] * inv; o.y = (float)p4[1] * inv;
        o.z = (float)p4[2] * inv; o.w = (float)p4[3] * inv;
        *reinterpret_cast<float4*>(arow + col) = o;
      }
    }
  };

  // ---------- ctx finalize for one block (store waves) ----------
  auto ctx_fin = [&](int blk) {
    const float* sp = sums_p + (blk & 3) * (8 * kQB);
    const int sw = wid - 4;
    const int row = sw * 4 + (lane >> 4);
    const int d = l15 * 4;
    float l = 0.f;
#pragma unroll
    for (int w = 0; w < 8; ++w) l += sp[w * kQB + row];
    const float inv = 1.0f / l;
    const float* c0 = cpart + ((blk & 1) * 2 + 0) * (kQB * kCStride) + row * kCStride + d;
    const float* c1 = cpart + ((blk & 1) * 2 + 1) * (kQB * kCStride) + row * kCStride + d;
    const float4 a = *reinterpret_cast<const float4*>(c0);
    const float4 e = *reinterpret_cast<const float4*>(c1);
    float4 o;
    o.x = (a.x + e.x) * inv; o.y = (a.y + e.y) * inv;
    o.z = (a.z + e.z) * inv; o.w = (a.w + e.w) * inv;
    *reinterpret_cast<float4*>(
        ctxOut + ((size_t)(b * kSQ) + q_base + blk * kQB + row) * kD + d) = o;
  };

  // ---------- pipeline ----------
  pass1(0, wid * 256, 16);                 // prologue: all 8 waves split keys
  __syncthreads();
  for (int j = 0; j < kNBLK; ++j) {
    if (wid < 4) {
      if (j + 1 < kNBLK) pass1(j + 1, wid * 512, 32);
      pv_phase(j);
    } else {
      attn_store(j);
      if (j > 0) ctx_fin(j - 1);
    }
    __syncthreads();
  }
  if (wid >= 4) ctx_fin(kNBLK - 1);
}

extern "C" void kernel_launch(void* const* d_in, const int* in_sizes, int n_in,
                              void* d_out, int out_size, void* d_ws, size_t ws_size,
                              hipStream_t stream)
{
  const float* Q = (const float*)d_in[0];
  const float* K = (const float*)d_in[1];
  const float* V = (const float*)d_in[2];
  const int*   M = (const int*)d_in[3];   // bool mask pushed as 4-byte words
  float* ctx  = (float*)d_out;
  float* attn = (float*)d_out + (size_t)kB * kSQ * kD;

  dim3 grid(kB * kSQ / (kQB * kNBLK));    // 256
  dim3 block(512);
  hipLaunchKernelGGL(sdpa_pipe, grid, block, 0, stream, Q, K, V, M, ctx, attn);
}